// Round 3
// baseline (610.683 us; speedup 1.0000x reference)
//
#include <hip/hip_runtime.h>

#define HH  512
#define WW  512
#define HPP 64
#define WPP 2048
#define BB  4
#define CC  64

// Fill the center "drop" disk (pixels the scatter never writes) from ref_feat.
// Analytic recomputation of index_y <= 0, with +1e-3 margin: pixels in the
// margin band are also written by the sampler (which runs AFTER this kernel
// on the same stream), so any overlap is overwritten with the correct value.
// The disk (depth <= ~16.22px around center 255.5) fits in rows/cols 240..271.
__global__ __launch_bounds__(256) void fill_disk(
    const float* __restrict__ ref, float* __restrict__ out) {
    int t  = blockIdx.x * 256 + threadIdx.x;   // 0..1023 -> 32x32 box
    int bc = blockIdx.y;                       // 0..255 = b*C+c plane
    int r = 240 + (t >> 5);
    int c = 240 + (t & 31);
    float yyc = (float)r - 255.5f;
    float xxc = (float)c - 255.5f;
    float depth = sqrtf(yyc * yyc + xxc * xxc);
    // numpy: index_y = depth / (256*sqrt(2)) * 67 - 3
    float iyv = depth * (67.0f / 362.03867196751236f) - 3.0f;
    if (iyv <= 1e-3f) {
        size_t off = (size_t)bc * (HH * WW) + (size_t)r * WW + c;
        out[off] = ref[off];
    }
}

// Scatter (gx,gy) into a pixel-indexed map so the tiled sampler can look up
// its own pixel's coords without knowing the mask-compacted index n.
// Map is pre-filled with 0xFF bytes (= NaN) by hipMemsetAsync; NaN fails the
// (x > -2) validity test, so never-scattered (disk) pixels are skipped.
__global__ __launch_bounds__(256) void scatter_map(
    const float* __restrict__ gx, const float* __restrict__ gy,
    const int* __restrict__ idx_y, const int* __restrict__ idx_x,
    float2* __restrict__ map, int N) {
    int n = blockIdx.x * 256 + threadIdx.x;
    if (n >= N) return;
    map[idx_y[n] * WW + idx_x[n]] = make_float2(gx[n], gy[n]);
}

// 8-byte, 4-aligned pair load (x0 and x0+1 taps in one VMEM op where the
// backend supports unaligned dwordx2; otherwise two dwords — still correct).
struct __attribute__((packed, aligned(4))) fpair { float lo, hi; };

// v3: tiled bilinear sample + scatter, 2-D wave footprint.
//
// v2 was TA/TCP transaction-bound (41 cyc/VMEM-instr, VALUBusy 8%, HBM 22%):
// a wave = 64 consecutive pixels of ONE cart row, whose polar x-coords spread
// by ~326/r columns per pixel -> each pair-gather split into ~35+ cache-line
// transactions. Here each wave covers an 8x8 cart block (block = 16x16 tile,
// 4 waves), shrinking the angular footprint ~8x -> ~8 lines per gather.
// Pixel coords come from the pixel-indexed map (exact same gx/gy values as
// v2; no analytic mask/coord recomputation -> numerics identical).
// Plain stores (not nontemporal): stores are now 8x32B segments per instr;
// L2 write-back merges neighboring waves' halves into full lines.
__global__ __launch_bounds__(256) void sample_tiled(
    const float* __restrict__ polar, const float2* __restrict__ map,
    float* __restrict__ out) {
    // --- bijective XCD swizzle over 1024 tiles (1024 % 8 == 0) ---
    int bid = blockIdx.x;
    int swz = ((bid & 7) << 7) + (bid >> 3);
    int tile_r = swz >> 5, tile_c = swz & 31;   // 32x32 tiles of 16x16 px

    int t = (int)threadIdx.x;
    int wave = t >> 6, lane = t & 63;
    int r = tile_r * 16 + ((wave >> 1) << 3) + (lane >> 3);
    int c = tile_c * 16 + ((wave & 1) << 3) + (lane & 7);

    float2 mv = map[r * WW + c];
    if (!(mv.x > -2.0f)) return;     // NaN sentinel -> unmasked (disk) pixel
    int b = blockIdx.y;

    float gxv = mv.x, gyv = mv.y;
    float ixf = (gxv + 1.0f) * ((WPP - 1) * 0.5f);
    float iyf = (gyv + 1.0f) * ((HPP - 1) * 0.5f);
    float x0f = floorf(ixf), y0f = floorf(iyf);
    float wx1 = ixf - x0f,  wy1 = iyf - y0f;
    float wx0 = 1.0f - wx1, wy0 = 1.0f - wy1;
    int x0 = (int)x0f, y0 = (int)y0f;
    int x1 = x0 + 1,   y1 = y0 + 1;

    bool vx0 = (x0 >= 0) & (x0 < WPP);
    bool vx1 = (x1 >= 0) & (x1 < WPP);
    bool vy0 = (y0 >= 0) & (y0 < HPP);
    bool vy1 = (y1 >= 0) & (y1 < HPP);
    float w00 = (vx0 && vy0) ? wx0 * wy0 : 0.0f;
    float w01 = (vx1 && vy0) ? wx1 * wy0 : 0.0f;
    float w10 = (vx0 && vy1) ? wx0 * wy1 : 0.0f;
    float w11 = (vx1 && vy1) ? wx1 * wy1 : 0.0f;

    int xs  = min(max(x0, 0), WPP - 2);
    int ys0 = min(max(y0, 0), HPP - 1);
    int ys1 = min(max(y1, 0), HPP - 1);

    const char* pb = (const char*)polar + (size_t)b * ((size_t)CC * HPP * WPP * 4);
    char*       ob = (char*)out + (size_t)b * ((size_t)CC * HH * WW * 4)
                               + (size_t)(r * WW + c) * 4;
    unsigned offA = (unsigned)(ys0 * WPP + xs) * 4u;
    unsigned offB = (unsigned)(ys1 * WPP + xs) * 4u;

    #pragma unroll 8
    for (int ch = 0; ch < CC; ++ch) {
        fpair a01 = *(const fpair*)(pb + offA);  // row y0: taps x0, x0+1
        fpair b01 = *(const fpair*)(pb + offB);  // row y1: taps x0, x0+1
        float v = a01.lo * w00 + a01.hi * w01 + b01.lo * w10 + b01.hi * w11;
        *(float*)ob = v;
        pb += (size_t)HPP * WPP * 4;
        ob += (size_t)HH * WW * 4;
    }
}

// ---- v2 fallback (used only if ws_size < 2MB): verified at 209us ----
__global__ __launch_bounds__(256) void sample_scatter_v2(
    const float* __restrict__ polar,
    const float* __restrict__ gx, const float* __restrict__ gy,
    const int* __restrict__ idx_y, const int* __restrict__ idx_x,
    float* __restrict__ out, int N) {
    int nwg = gridDim.x;
    int bid = blockIdx.x;
    int q = nwg >> 3, rr = nwg & 7;
    int xcd = bid & 7, lid = bid >> 3;
    int swz = (xcd < rr ? xcd * (q + 1) : rr * (q + 1) + (xcd - rr) * q) + lid;

    int n = swz * 256 + (int)threadIdx.x;
    if (n >= N) return;
    int b = blockIdx.y;

    float gxv = gx[n], gyv = gy[n];
    float ixf = (gxv + 1.0f) * ((WPP - 1) * 0.5f);
    float iyf = (gyv + 1.0f) * ((HPP - 1) * 0.5f);
    float x0f = floorf(ixf), y0f = floorf(iyf);
    float wx1 = ixf - x0f,  wy1 = iyf - y0f;
    float wx0 = 1.0f - wx1, wy0 = 1.0f - wy1;
    int x0 = (int)x0f, y0 = (int)y0f;
    int x1 = x0 + 1,   y1 = y0 + 1;

    bool vx0 = (x0 >= 0) & (x0 < WPP);
    bool vx1 = (x1 >= 0) & (x1 < WPP);
    bool vy0 = (y0 >= 0) & (y0 < HPP);
    bool vy1 = (y1 >= 0) & (y1 < HPP);
    float w00 = (vx0 && vy0) ? wx0 * wy0 : 0.0f;
    float w01 = (vx1 && vy0) ? wx1 * wy0 : 0.0f;
    float w10 = (vx0 && vy1) ? wx0 * wy1 : 0.0f;
    float w11 = (vx1 && vy1) ? wx1 * wy1 : 0.0f;

    int xs  = min(max(x0, 0), WPP - 2);
    int ys0 = min(max(y0, 0), HPP - 1);
    int ys1 = min(max(y1, 0), HPP - 1);

    int oy = idx_y[n], ox = idx_x[n];
    const char* pb = (const char*)polar + (size_t)b * ((size_t)CC * HPP * WPP * 4);
    char*       ob = (char*)out + (size_t)b * ((size_t)CC * HH * WW * 4)
                               + (size_t)(oy * WW + ox) * 4;
    unsigned offA = (unsigned)(ys0 * WPP + xs) * 4u;
    unsigned offB = (unsigned)(ys1 * WPP + xs) * 4u;

    #pragma unroll 8
    for (int ch = 0; ch < CC; ++ch) {
        fpair a01 = *(const fpair*)(pb + offA);
        fpair b01 = *(const fpair*)(pb + offB);
        float v = a01.lo * w00 + a01.hi * w01 + b01.lo * w10 + b01.hi * w11;
        __builtin_nontemporal_store(v, (float*)ob);
        pb += (size_t)HPP * WPP * 4;
        ob += (size_t)HH * WW * 4;
    }
}

extern "C" void kernel_launch(void* const* d_in, const int* in_sizes, int n_in,
                              void* d_out, int out_size, void* d_ws, size_t ws_size,
                              hipStream_t stream) {
    const float* polar = (const float*)d_in[0];
    const float* ref   = (const float*)d_in[1];
    const float* gxp   = (const float*)d_in[2];
    const float* gyp   = (const float*)d_in[3];
    const int*   iyp   = (const int*)d_in[4];
    const int*   ixp   = (const int*)d_in[5];
    float* out = (float*)d_out;
    int N = in_sizes[2];

    const size_t map_bytes = (size_t)HH * WW * sizeof(float2);   // 2 MB

    fill_disk<<<dim3(4, BB * CC), 256, 0, stream>>>(ref, out);

    if (ws_size >= map_bytes) {
        float2* map = (float2*)d_ws;
        // 0xFF bytes = NaN -> fails (x > -2) validity test in sample_tiled.
        hipMemsetAsync(map, 0xFF, map_bytes, stream);
        scatter_map<<<dim3((N + 255) / 256), 256, 0, stream>>>(
            gxp, gyp, iyp, ixp, map, N);
        sample_tiled<<<dim3(1024, BB), 256, 0, stream>>>(polar, map, out);
    } else {
        sample_scatter_v2<<<dim3((N + 255) / 256, BB), 256, 0, stream>>>(
            polar, gxp, gyp, iyp, ixp, out, N);
    }
}